// Round 9
// baseline (774.255 us; speedup 1.0000x reference)
//
#include <hip/hip_runtime.h>
#include <hip/hip_bf16.h>

typedef float f32x4 __attribute__((ext_vector_type(4)));
typedef int   i32x4 __attribute__((ext_vector_type(4)));
typedef short s16x8 __attribute__((ext_vector_type(8)));
typedef unsigned short u16;

#define NGP 32       // group-pairs; each = 2 tiles x 16 rows
#define BT 16        // rows per tile
#define NWG 256      // 32 pairs x 8 h-slices
#define NTH 1024     // 16 waves -> 4 waves/SIMD
#define PREPTH 256
#define H 128
#define VW 256
#define NI 64
#define NSTEPS 64

// ws BYTE layout:
#define OFF_FRAG16 0        // u16 frags: W1 (32768 u16) + W2 (65536 u16) = 196608 B
#define OFF_WMQ    196608   // i8 frags [slice8][l21][kk4][lane64][16] = 688128 B
#define OFF_BMF    884736   // f32 [slice8][l21][hh16] = 10752 B
#define OFF_SCF    895488   // f32[128]
#define OFF_SINV   896000   // f32[128]
#define OFF_YBUF   896512   // u32 [64 tile][2 parity][2048] = 1 MB
#define YBUF_BYTES 1048576

#define MFMA_BF16(a,b,c) __builtin_amdgcn_mfma_f32_16x16x32_bf16(a,b,c,0,0,0)
#define MFMA_I8(a,b,c)   __builtin_amdgcn_mfma_i32_16x16x64_i8(a,b,c,0,0,0)

__device__ __forceinline__ u16 bf16u(float f) {
  union { float f; unsigned u; } x; x.f = f;
  return (u16)((x.u + 0x7fffu + ((x.u >> 16) & 1u)) >> 16);  // RNE
}
__device__ __forceinline__ float b2f(u16 u) {
  union { unsigned u; float f; } x; x.u = ((unsigned)u) << 16;
  return x.f;
}

// -------- prep 1: per-h max of |Wm| -> scales --------
__global__ void prep_scales(const float* __restrict__ Wm, char* __restrict__ ws) {
  __shared__ float red[4];
  const int tid = threadIdx.x;
  const int h = blockIdx.x;
  float m = 0.f;
  for (int i = tid; i < 21 * VW; i += PREPTH) m = fmaxf(m, fabsf(Wm[h * 21 * VW + i]));
  for (int off = 32; off > 0; off >>= 1) m = fmaxf(m, __shfl_down(m, off));
  if ((tid & 63) == 0) red[tid >> 6] = m;
  __syncthreads();
  if (tid == 0) {
    m = fmaxf(fmaxf(red[0], red[1]), fmaxf(red[2], red[3]));
    m = fmaxf(m, 1e-20f);
    ((float*)(ws + OFF_SCF))[h]  = m / 16129.f;   // max/(127*127)
    ((float*)(ws + OFF_SINV))[h] = 127.f / m;
  }
}

// -------- prep 2: pack W1/W2 bf16 frags, Wm i8 frags, bm slices --------
__global__ void prep_pack(const float* __restrict__ Wvf1, const float* __restrict__ Wvf2,
                          const float* __restrict__ Wm, const float* __restrict__ bmv,
                          char* __restrict__ ws) {
  int idx = blockIdx.x * blockDim.x + threadIdx.x;
  if (idx < 98304) {
    u16* w16 = (u16*)(ws + OFF_FRAG16);
    float val;
    if (idx < 32768) {
      int e = idx;
      int j = e & 7, ln = (e >> 3) & 63, nt = (e >> 9) & 15, kk = e >> 13;
      val = Wvf1[(nt * 16 + (ln & 15)) * H + kk * 32 + (ln >> 4) * 8 + j];
    } else {
      int e = idx - 32768;
      int j = e & 7, ln = (e >> 3) & 63, nt = (e >> 9) & 15, kk = e >> 13;
      val = Wvf2[(nt * 16 + (ln & 15)) * VW + kk * 32 + (ln >> 4) * 8 + j];
    }
    w16[idx] = bf16u(val);
  } else if (idx < 98304 + 688128) {
    int b = idx - 98304;
    int j = b & 15, lane = (b >> 4) & 63, kk = (b >> 10) & 3, rem = b >> 12;
    int l = rem % 21, nt = rem / 21;
    int h = nt * 16 + (lane & 15);
    int w = kk * 64 + (lane >> 4) * 16 + j;
    float sinv = ((const float*)(ws + OFF_SINV))[h];
    float val = Wm[(size_t)(h * 21 + l) * VW + w];
    int q = (int)lrintf(val * sinv);
    q = min(127, max(-127, q));
    ((signed char*)(ws + OFF_WMQ))[b] = (signed char)q;
  } else if (idx < 98304 + 688128 + 2688) {
    int b = idx - (98304 + 688128);
    int hh = b & 15, rem = b >> 4;
    int l = rem % 21, nt = rem / 21;
    ((float*)(ws + OFF_BMF))[b] = bmv[(nt * 16 + hh) * 21 + l];
  }
}

// -------- main persistent kernel: 4-phase dual-tile pipeline, 16 waves --------
__global__ __launch_bounds__(NTH, 1) void rde_main(
    const float* __restrict__ logsig, const float* __restrict__ x0,
    const float* __restrict__ W1, const float* __restrict__ b1,
    const float* __restrict__ bvf1, const float* __restrict__ bvf2,
    const float* __restrict__ W2, const float* __restrict__ b2,
    char* __restrict__ ws, float* __restrict__ out) {
  __shared__ __align__(16) signed char WmL[86016];    // i8 Wm slice (shared)
  __shared__ __align__(16) u16   YB [2][BT][H + 8];   // per-tile bf16 y
  __shared__ __align__(16) u16   V1R[BT][VW + 8];     // time-shared between tiles
  __shared__ __align__(16) signed char V2QH[4096];    // time-shared
  __shared__ __align__(16) float LSF[2][2][21][BT];   // [tile][parity][l][r]
  __shared__ __align__(16) float part[16][BT][17];    // time-shared, one slot per wave
  __shared__ __align__(16) float bmL[336];
  __shared__ float scL[16];
  __shared__ float LG[32][10];

  const int tid = threadIdx.x;
  const int lane = tid & 63;
  const int wv = tid >> 6;     // 0..15
  const int c = lane & 15;
  const int kg = lane >> 4;
  const int bid = blockIdx.x;
  const int Gp = (bid & 7) * 4 + (bid >> 6);  // 0..31; pair members share bid%8 (XCD heuristic)
  const int t = (bid >> 3) & 7;               // h-slice 0..7
  const int b0 = Gp * 32;
  unsigned* __restrict__ ybuf = (unsigned*)(ws + OFF_YBUF);
  const s16x8* __restrict__ fr16 = (const s16x8*)(ws + OFF_FRAG16);
  const f32x4 zf = {0.f, 0.f, 0.f, 0.f};
  const i32x4 zi = {0, 0, 0, 0};

  // persistent register weights: wave wv owns n-tile wv (16 n-tiles)
  s16x8 w1r[4], w2r[8];
#pragma unroll
  for (int kk = 0; kk < 4; ++kk) w1r[kk] = fr16[(kk * 16 + wv) * 64 + lane];
#pragma unroll
  for (int kk = 0; kk < 8; ++kk) w2r[kk] = fr16[4096 + (kk * 16 + wv) * 64 + lane];
  const float bv1 = bvf1[wv * 16 + c];
  const float bv2 = bvf2[wv * 16 + c];

  {  // Wm slice -> LDS (once)
    const i32x4* wsrc = (const i32x4*)(ws + OFF_WMQ + t * 86016);
    i32x4* wdst = (i32x4*)WmL;
    for (int e = tid; e < 5376; e += NTH) wdst[e] = wsrc[e];
  }
  if (tid < 16) scL[tid] = ((const float*)(ws + OFF_SCF))[t * 16 + tid];
  if (tid < 336) bmL[tid] = ((const float*)(ws + OFF_BMF))[t * 336 + tid];

  // y0 = x0 @ W1^T + b1 for both tiles (full YB + own state elements)
  for (int e = tid; e < 2 * BT * H; e += NTH) {
    int tt = e >> 11, r = (e >> 7) & 15, h = e & 127;
    float a = b1[h];
#pragma unroll
    for (int d = 0; d < 6; ++d) a += x0[(b0 + tt * 16 + r) * 6 + d] * W1[h * 6 + d];
    YB[tt][r][h] = bf16u(a);
  }
  float y0s = 0.f, y1s = 0.f, yp0s = 0.f, yp1s = 0.f;
  float bmd0 = 0.f, bmd1 = 0.f;   // cached bm.ls per tile (valid within an interval)
  if (tid < 256) {
    int r = tid >> 4, hh = tid & 15, h = t * 16 + hh;
    float a0 = b1[h], a1 = b1[h];
#pragma unroll
    for (int d = 0; d < 6; ++d) {
      a0 += x0[(b0 + r) * 6 + d] * W1[h * 6 + d];
      a1 += x0[(b0 + 16 + r) * 6 + d] * W1[h * 6 + d];
    }
    y0s = a0; y1s = a1;
  }

  // ---- pipeline stage helpers ----
  auto STAGE = [&](int T, int iv) {
    if (tid < BT * 21) {
      int r = tid / 21, l = tid - r * 21;
      LSF[T][iv & 1][l][r] = logsig[((size_t)(b0 + T * 16 + r) * NI + iv) * 22 + 1 + l];
    }
  };
  auto S1 = [&](int T) {  // YB[T] -> V1R cols [wv*16, wv*16+16)
    s16x8 ay0 = *(const s16x8*)&YB[T][c][0 * 32 + kg * 8];
    s16x8 ay1 = *(const s16x8*)&YB[T][c][1 * 32 + kg * 8];
    s16x8 ay2 = *(const s16x8*)&YB[T][c][2 * 32 + kg * 8];
    s16x8 ay3 = *(const s16x8*)&YB[T][c][3 * 32 + kg * 8];
    f32x4 p = MFMA_BF16(ay0, w1r[0], zf);
    p = MFMA_BF16(ay1, w1r[1], p);
    p = MFMA_BF16(ay2, w1r[2], p);
    p = MFMA_BF16(ay3, w1r[3], p);
#pragma unroll
    for (int q = 0; q < 4; ++q)
      V1R[kg * 4 + q][wv * 16 + c] = bf16u(fmaxf(p[q] + bv1, 0.f));
  };
  auto S2 = [&]() {  // V1R -> V2QH cols [wv*16, wv*16+16) (tanh + i8)
    s16x8 av0 = *(const s16x8*)&V1R[c][0 * 32 + kg * 8];
    s16x8 av1 = *(const s16x8*)&V1R[c][1 * 32 + kg * 8];
    s16x8 av2 = *(const s16x8*)&V1R[c][2 * 32 + kg * 8];
    s16x8 av3 = *(const s16x8*)&V1R[c][3 * 32 + kg * 8];
    f32x4 pLo = MFMA_BF16(av0, w2r[0], zf);
    pLo = MFMA_BF16(av1, w2r[1], pLo);
    pLo = MFMA_BF16(av2, w2r[2], pLo);
    pLo = MFMA_BF16(av3, w2r[3], pLo);
    s16x8 av4 = *(const s16x8*)&V1R[c][4 * 32 + kg * 8];
    s16x8 av5 = *(const s16x8*)&V1R[c][5 * 32 + kg * 8];
    s16x8 av6 = *(const s16x8*)&V1R[c][6 * 32 + kg * 8];
    s16x8 av7 = *(const s16x8*)&V1R[c][7 * 32 + kg * 8];
    f32x4 pHi = MFMA_BF16(av4, w2r[4], zf);
    pHi = MFMA_BF16(av5, w2r[5], pHi);
    pHi = MFMA_BF16(av6, w2r[6], pHi);
    pHi = MFMA_BF16(av7, w2r[7], pHi);
#pragma unroll
    for (int q = 0; q < 4; ++q) {
      float x = pLo[q] + pHi[q] + bv2;
      float e2 = __expf(2.f * x);
      float t127 = fmaf(-254.f, __builtin_amdgcn_rcpf(e2 + 1.f), 127.f);  // 127*tanh
      // v2[row=kg*4+q][col=wv*16+c] in frag-linear layout
      int bo = (((wv >> 2) * 64) + (wv & 3) * 16 + kg * 4 + q) * 16 + c;
      V2QH[bo] = (signed char)(int)rintf(t127);
    }
  };
  auto S3 = [&](int T, int lsb_) {  // V2QH x WmL -> part[wv] (ls-folded), 1-2 l's per wave
    i32x4 aih0 = *(const i32x4*)&V2QH[(0 * 64 + lane) * 16];
    i32x4 aih1 = *(const i32x4*)&V2QH[(1 * 64 + lane) * 16];
    i32x4 aih2 = *(const i32x4*)&V2QH[(2 * 64 + lane) * 16];
    i32x4 aih3 = *(const i32x4*)&V2QH[(3 * 64 + lane) * 16];
    const int nl3 = (wv < 5) ? 2 : 1;
    const int lb3 = (wv < 5) ? 2 * wv : 10 + (wv - 5);
    f32x4 acc = zf;
#pragma unroll
    for (int li = 0; li < 2; ++li) {
      if (li < nl3) {
        int l = lb3 + li;
        const i32x4* bp = (const i32x4*)WmL + l * 256 + lane;
        i32x4 bq0 = bp[0], bq1 = bp[64], bq2 = bp[128], bq3 = bp[192];
        i32x4 PH = MFMA_I8(aih0, bq0, zi);
        PH = MFMA_I8(aih1, bq1, PH);
        PH = MFMA_I8(aih2, bq2, PH);
        PH = MFMA_I8(aih3, bq3, PH);
        f32x4 ls4 = *(const f32x4*)&LSF[T][lsb_][l][kg * 4];
#pragma unroll
        for (int q = 0; q < 4; ++q) acc[q] += ls4[q] * (float)PH[q];
      }
    }
#pragma unroll
    for (int q = 0; q < 4; ++q) part[wv][kg * 4 + q][c] = acc[q];
  };
  auto S4 = [&](int T, int jj, int lsb_, float& y, float& yp, float& bmdc) {
    if (tid < 256) {
      int r = tid >> 4, hh = tid & 15;
      float s = 0.f;
#pragma unroll
      for (int w = 0; w < 16; ++w) s += part[w][r][hh];
      if (jj == 0 || (jj & 1)) {   // interval changed -> recompute bm.ls
        float bmd = 0.f;
#pragma unroll
        for (int l = 0; l < 21; ++l) bmd += LSF[T][lsb_][l][r] * bmL[l * 16 + hh];
        bmdc = bmd;
      }
      float raw = scL[hh] * s + bmdc;
      float yn;
      if (!(jj & 1)) { yp = y + 0.5f * raw; yn = y + raw; }
      else           { y = yp + 0.5f * raw; yn = y; }
      unsigned v = ((unsigned)(jj + 1) << 16) | (unsigned)bf16u(yn);
      __hip_atomic_store(&ybuf[((Gp * 2 + T) * 2 + (jj & 1)) * 2048 + r * 128 + t * 16 + hh],
                         v, __ATOMIC_RELAXED, __HIP_MEMORY_SCOPE_AGENT);
    }
  };
  auto S5 = [&](int T, int jj) {  // poll 2 contiguous words, rebuild YB[T]
    const unsigned tg = (unsigned)(jj + 1);
    const unsigned* pb = ybuf + ((Gp * 2 + T) * 2 + (jj & 1)) * 2048 + tid * 2;
    unsigned v0, v1;
#pragma unroll 1
    for (int sp = 0; sp < 60000; ++sp) {
      v0 = __hip_atomic_load(pb,     __ATOMIC_RELAXED, __HIP_MEMORY_SCOPE_AGENT);
      v1 = __hip_atomic_load(pb + 1, __ATOMIC_RELAXED, __HIP_MEMORY_SCOPE_AGENT);
      if (min(v0 >> 16, v1 >> 16) == tg) break;
    }
    int e0 = tid * 2, r = e0 >> 7, h0 = e0 & 127;
    *(unsigned*)&YB[T][r][h0] = (v0 & 0xffffu) | (v1 << 16);
  };

  __syncthreads();

  // ---- pipeline prologue: tile B runs S1,S2 of sub-step 0
  STAGE(1, 0);
  __syncthreads();
  S1(1);
  __syncthreads();
  S2();
  __syncthreads();

#pragma unroll 1
  for (int j = 0; j < 2 * NSTEPS; ++j) {
    const int step_ = j >> 1, sub_ = j & 1;
    const int lsb_ = (sub_ ? step_ : (step_ > 0 ? step_ - 1 : 0)) & 1;
    // p0: S1(A,j) || S3(B,j)
    if (!sub_) STAGE(0, step_);
    S1(0);
    S3(1, lsb_);
    __syncthreads();
    // p1: store B early, compute S2(A), poll B late
    S4(1, j, lsb_, y1s, yp1s, bmd1);
    S2();
    S5(1, j);
    __syncthreads();
    // p2: S3(A,j) || S1(B,j+1)
    S3(0, lsb_);
    if (j < 2 * NSTEPS - 1) {
      if (sub_) STAGE(1, (j + 1) >> 1);
      S1(1);
    }
    __syncthreads();
    // p3: store A early, compute S2(B,j+1), poll A late
    S4(0, j, lsb_, y0s, yp0s, bmd0);
    if (j < 2 * NSTEPS - 1) S2();
    S5(0, j);
    __syncthreads();
  }

  // ---- logits + softmax (slice-0 WG of each pair; 32 rows)
  if (t == 0) {
    for (int e = tid; e < 32 * 10; e += NTH) {
      int rr = e / 10, cc = e - rr * 10;
      float a = b2[cc];
#pragma unroll 4
      for (int h = 0; h < H; ++h) a += b2f(YB[rr >> 4][rr & 15][h]) * W2[cc * H + h];
      LG[rr][cc] = a;
    }
    __syncthreads();
    if (tid < 32) {
      float mx = -1e30f;
#pragma unroll
      for (int cc = 0; cc < 10; ++cc) mx = fmaxf(mx, LG[tid][cc]);
      float ex[10]; float s = 0.f;
#pragma unroll
      for (int cc = 0; cc < 10; ++cc) { ex[cc] = expf(LG[tid][cc] - mx); s += ex[cc]; }
      float inv = 1.f / s;
#pragma unroll
      for (int cc = 0; cc < 10; ++cc) out[(b0 + tid) * 10 + cc] = ex[cc] * inv;
    }
  }
}

extern "C" void kernel_launch(void* const* d_in, const int* in_sizes, int n_in,
                              void* d_out, int out_size, void* d_ws, size_t ws_size,
                              hipStream_t stream) {
  (void)in_sizes; (void)n_in; (void)out_size; (void)ws_size;
  const float* logsig = (const float*)d_in[1];
  const float* x0     = (const float*)d_in[2];
  const float* Wvf1   = (const float*)d_in[3];
  const float* bvf1   = (const float*)d_in[4];
  const float* Wvf2   = (const float*)d_in[5];
  const float* bvf2   = (const float*)d_in[6];
  const float* Wm     = (const float*)d_in[7];
  const float* bmv    = (const float*)d_in[8];
  const float* W1     = (const float*)d_in[9];
  const float* b1     = (const float*)d_in[10];
  const float* W2     = (const float*)d_in[11];
  const float* b2     = (const float*)d_in[12];
  char* ws = (char*)d_ws;

  prep_scales<<<128, PREPTH, 0, stream>>>(Wm, ws);
  prep_pack<<<3083, PREPTH, 0, stream>>>(Wvf1, Wvf2, Wm, bmv, ws);
  hipMemsetAsync(ws + OFF_YBUF, 0, YBUF_BYTES, stream);  // kill stale tags each call
  rde_main<<<NWG, NTH, 0, stream>>>(logsig, x0, W1, b1, bvf1, bvf2, W2, b2, ws,
                                    (float*)d_out);
}

// Round 10
// 600.046 us; speedup vs baseline: 1.2903x; 1.2903x over previous
//
#include <hip/hip_runtime.h>
#include <hip/hip_bf16.h>

typedef float f32x4 __attribute__((ext_vector_type(4)));
typedef int   i32x4 __attribute__((ext_vector_type(4)));
typedef short s16x8 __attribute__((ext_vector_type(8)));
typedef unsigned short u16;

#define NGP 32       // group-pairs; each = 2 tiles x 16 rows
#define BT 16        // rows per tile
#define NWG 256      // 32 pairs x 8 h-slices
#define NTH 512      // 8 waves
#define PREPTH 256
#define H 128
#define VW 256
#define NI 64
#define NSTEPS 64

// ws BYTE layout:
#define OFF_FRAG16 0        // u16 frags: W1 (32768 u16) + W2 (65536 u16) = 196608 B
#define OFF_WMQ    196608   // i8 frags [slice8][l21][kk4][lane64][16] = 688128 B
#define OFF_BMF    884736   // f32 [slice8][l21][hh16] = 10752 B
#define OFF_SCF    895488   // f32[128]
#define OFF_SINV   896000   // f32[128]
#define OFF_YBUF   896512   // u32 [64 tile][2 parity][2048] = 1 MB
#define YBUF_BYTES 1048576

#define MFMA_BF16(a,b,c) __builtin_amdgcn_mfma_f32_16x16x32_bf16(a,b,c,0,0,0)
#define MFMA_I8(a,b,c)   __builtin_amdgcn_mfma_i32_16x16x64_i8(a,b,c,0,0,0)

__device__ __forceinline__ u16 bf16u(float f) {
  union { float f; unsigned u; } x; x.f = f;
  return (u16)((x.u + 0x7fffu + ((x.u >> 16) & 1u)) >> 16);  // RNE
}
__device__ __forceinline__ float b2f(u16 u) {
  union { unsigned u; float f; } x; x.u = ((unsigned)u) << 16;
  return x.f;
}

// -------- prep 1: per-h max of |Wm| -> scales --------
__global__ void prep_scales(const float* __restrict__ Wm, char* __restrict__ ws) {
  __shared__ float red[4];
  const int tid = threadIdx.x;
  const int h = blockIdx.x;
  float m = 0.f;
  for (int i = tid; i < 21 * VW; i += PREPTH) m = fmaxf(m, fabsf(Wm[h * 21 * VW + i]));
  for (int off = 32; off > 0; off >>= 1) m = fmaxf(m, __shfl_down(m, off));
  if ((tid & 63) == 0) red[tid >> 6] = m;
  __syncthreads();
  if (tid == 0) {
    m = fmaxf(fmaxf(red[0], red[1]), fmaxf(red[2], red[3]));
    m = fmaxf(m, 1e-20f);
    ((float*)(ws + OFF_SCF))[h]  = m / 16129.f;   // max/(127*127)
    ((float*)(ws + OFF_SINV))[h] = 127.f / m;
  }
}

// -------- prep 2: pack W1/W2 bf16 frags, Wm i8 frags, bm slices --------
__global__ void prep_pack(const float* __restrict__ Wvf1, const float* __restrict__ Wvf2,
                          const float* __restrict__ Wm, const float* __restrict__ bmv,
                          char* __restrict__ ws) {
  int idx = blockIdx.x * blockDim.x + threadIdx.x;
  if (idx < 98304) {
    u16* w16 = (u16*)(ws + OFF_FRAG16);
    float val;
    if (idx < 32768) {
      int e = idx;
      int j = e & 7, ln = (e >> 3) & 63, nt = (e >> 9) & 15, kk = e >> 13;
      val = Wvf1[(nt * 16 + (ln & 15)) * H + kk * 32 + (ln >> 4) * 8 + j];
    } else {
      int e = idx - 32768;
      int j = e & 7, ln = (e >> 3) & 63, nt = (e >> 9) & 15, kk = e >> 13;
      val = Wvf2[(nt * 16 + (ln & 15)) * VW + kk * 32 + (ln >> 4) * 8 + j];
    }
    w16[idx] = bf16u(val);
  } else if (idx < 98304 + 688128) {
    int b = idx - 98304;
    int j = b & 15, lane = (b >> 4) & 63, kk = (b >> 10) & 3, rem = b >> 12;
    int l = rem % 21, nt = rem / 21;
    int h = nt * 16 + (lane & 15);
    int w = kk * 64 + (lane >> 4) * 16 + j;
    float sinv = ((const float*)(ws + OFF_SINV))[h];
    float val = Wm[(size_t)(h * 21 + l) * VW + w];
    int q = (int)lrintf(val * sinv);
    q = min(127, max(-127, q));
    ((signed char*)(ws + OFF_WMQ))[b] = (signed char)q;
  } else if (idx < 98304 + 688128 + 2688) {
    int b = idx - (98304 + 688128);
    int hh = b & 15, rem = b >> 4;
    int l = rem % 21, nt = rem / 21;
    ((float*)(ws + OFF_BMF))[b] = bmv[(nt * 16 + hh) * 21 + l];
  }
}

// -------- main persistent kernel: 4-phase dual-tile pipeline, conflict-free stores --------
__global__ __launch_bounds__(NTH, 1) void rde_main(
    const float* __restrict__ logsig, const float* __restrict__ x0,
    const float* __restrict__ W1, const float* __restrict__ b1,
    const float* __restrict__ bvf1, const float* __restrict__ bvf2,
    const float* __restrict__ W2, const float* __restrict__ b2,
    char* __restrict__ ws, float* __restrict__ out) {
  __shared__ __align__(16) signed char WmL[86016];    // i8 Wm slice (shared)
  __shared__ __align__(16) u16   YB [2][BT][H + 8];   // per-tile bf16 y
  __shared__ __align__(16) u16   V1F[4096];           // v1 bf16, FRAG-LINEAR, time-shared
  __shared__ __align__(16) signed char V2QH[4096];    // v2 i8, frag-linear, time-shared
  __shared__ __align__(16) float LSF[2][2][21][BT];   // [tile][parity][l][r]
  __shared__ __align__(16) float part[8][BT][17];     // time-shared
  __shared__ __align__(16) float bmL[336];
  __shared__ float scL[16];
  __shared__ float LG[32][10];

  const int tid = threadIdx.x;
  const int lane = tid & 63;
  const int wv = tid >> 6;     // 0..7
  const int c = lane & 15;
  const int kg = lane >> 4;
  const int bid = blockIdx.x;
  const int Gp = (bid & 7) * 4 + (bid >> 6);  // 0..31; pair members share bid%8 (XCD heuristic)
  const int t = (bid >> 3) & 7;               // h-slice 0..7
  const int b0 = Gp * 32;
  unsigned* __restrict__ ybuf = (unsigned*)(ws + OFF_YBUF);
  const s16x8* __restrict__ fr16 = (const s16x8*)(ws + OFF_FRAG16);
  const f32x4 zf = {0.f, 0.f, 0.f, 0.f};
  const i32x4 zi = {0, 0, 0, 0};

  // persistent register weights: wave handles output-feature tiles {2wv, 2wv+1}
  s16x8 w1r[2][4], w2r[2][8];
#pragma unroll
  for (int n = 0; n < 2; ++n) {
#pragma unroll
    for (int kk = 0; kk < 4; ++kk) w1r[n][kk] = fr16[(kk * 16 + wv * 2 + n) * 64 + lane];
#pragma unroll
    for (int kk = 0; kk < 8; ++kk) w2r[n][kk] = fr16[4096 + (kk * 16 + wv * 2 + n) * 64 + lane];
  }
  // per-feature biases for the swapped-output layout: thread holds features wv*32+n*16+kg*4+q
  f32x4 bv1v[2], bv2v[2];
#pragma unroll
  for (int n = 0; n < 2; ++n) {
    bv1v[n] = *(const f32x4*)&bvf1[wv * 32 + n * 16 + kg * 4];
    bv2v[n] = *(const f32x4*)&bvf2[wv * 32 + n * 16 + kg * 4];
  }

  {  // Wm slice -> LDS (once)
    const i32x4* wsrc = (const i32x4*)(ws + OFF_WMQ + t * 86016);
    i32x4* wdst = (i32x4*)WmL;
    for (int e = tid; e < 5376; e += NTH) wdst[e] = wsrc[e];
  }
  if (tid < 16) scL[tid] = ((const float*)(ws + OFF_SCF))[t * 16 + tid];
  if (tid < 336) bmL[tid] = ((const float*)(ws + OFF_BMF))[t * 336 + tid];

  // y0 = x0 @ W1^T + b1 for both tiles (full YB + own state elements)
  for (int e = tid; e < 2 * BT * H; e += NTH) {
    int tt = e >> 11, r = (e >> 7) & 15, h = e & 127;
    float a = b1[h];
#pragma unroll
    for (int d = 0; d < 6; ++d) a += x0[(b0 + tt * 16 + r) * 6 + d] * W1[h * 6 + d];
    YB[tt][r][h] = bf16u(a);
  }
  float y0s = 0.f, y1s = 0.f, yp0s = 0.f, yp1s = 0.f;
  float bmd0 = 0.f, bmd1 = 0.f;
  if (tid < 256) {
    int r = tid >> 4, hh = tid & 15, h = t * 16 + hh;
    float a0 = b1[h], a1 = b1[h];
#pragma unroll
    for (int d = 0; d < 6; ++d) {
      a0 += x0[(b0 + r) * 6 + d] * W1[h * 6 + d];
      a1 += x0[(b0 + 16 + r) * 6 + d] * W1[h * 6 + d];
    }
    y0s = a0; y1s = a1;
  }

  // ---- pipeline stage helpers ----
  auto STAGE = [&](int T, int iv) {
    if (tid < BT * 21) {
      int r = tid / 21, l = tid - r * 21;
      LSF[T][iv & 1][l][r] = logsig[((size_t)(b0 + T * 16 + r) * NI + iv) * 22 + 1 + l];
    }
  };
  // S1 (swapped): D[w][r] = relu(W1^T-frag x y-frag); pack 4 bf16 -> u64, conflict-free
  auto S1 = [&](int T) {
    s16x8 ay0 = *(const s16x8*)&YB[T][c][0 * 32 + kg * 8];
    s16x8 ay1 = *(const s16x8*)&YB[T][c][1 * 32 + kg * 8];
    s16x8 ay2 = *(const s16x8*)&YB[T][c][2 * 32 + kg * 8];
    s16x8 ay3 = *(const s16x8*)&YB[T][c][3 * 32 + kg * 8];
    f32x4 pA = MFMA_BF16(w1r[0][0], ay0, zf), pB = MFMA_BF16(w1r[1][0], ay0, zf);
    pA = MFMA_BF16(w1r[0][1], ay1, pA);  pB = MFMA_BF16(w1r[1][1], ay1, pB);
    pA = MFMA_BF16(w1r[0][2], ay2, pA);  pB = MFMA_BF16(w1r[1][2], ay2, pB);
    pA = MFMA_BF16(w1r[0][3], ay3, pA);  pB = MFMA_BF16(w1r[1][3], ay3, pB);
#pragma unroll
    for (int n = 0; n < 2; ++n) {
      f32x4 p = n ? pB : pA;
      unsigned lo = (unsigned)bf16u(fmaxf(p[0] + bv1v[n][0], 0.f)) |
                    ((unsigned)bf16u(fmaxf(p[1] + bv1v[n][1], 0.f)) << 16);
      unsigned hi = (unsigned)bf16u(fmaxf(p[2] + bv1v[n][2], 0.f)) |
                    ((unsigned)bf16u(fmaxf(p[3] + bv1v[n][3], 0.f)) << 16);
      // w = wv*32+n*16+kg*4+q -> frag-linear u64 slot
      int u64i = ((wv * 4 + n * 2 + (kg >> 1)) * 16 + c) * 2 + (kg & 1);
      ((unsigned long long*)V1F)[u64i] =
          (unsigned long long)lo | ((unsigned long long)hi << 32);
    }
  };
  // S2 (swapped): D[v][r] = tanh(W2^T-frag x v1-frag); pack 4 i8 -> u32, conflict-free
  auto S2 = [&]() {
    const s16x8* v1f8 = (const s16x8*)V1F;
    s16x8 av0 = v1f8[(0 * 4 + kg) * 16 + c];
    s16x8 av1 = v1f8[(1 * 4 + kg) * 16 + c];
    s16x8 av2 = v1f8[(2 * 4 + kg) * 16 + c];
    s16x8 av3 = v1f8[(3 * 4 + kg) * 16 + c];
    s16x8 av4 = v1f8[(4 * 4 + kg) * 16 + c];
    s16x8 av5 = v1f8[(5 * 4 + kg) * 16 + c];
    s16x8 av6 = v1f8[(6 * 4 + kg) * 16 + c];
    s16x8 av7 = v1f8[(7 * 4 + kg) * 16 + c];
    f32x4 pA = MFMA_BF16(w2r[0][0], av0, zf), pB = MFMA_BF16(w2r[1][0], av0, zf);
    pA = MFMA_BF16(w2r[0][1], av1, pA);  pB = MFMA_BF16(w2r[1][1], av1, pB);
    pA = MFMA_BF16(w2r[0][2], av2, pA);  pB = MFMA_BF16(w2r[1][2], av2, pB);
    pA = MFMA_BF16(w2r[0][3], av3, pA);  pB = MFMA_BF16(w2r[1][3], av3, pB);
    pA = MFMA_BF16(w2r[0][4], av4, pA);  pB = MFMA_BF16(w2r[1][4], av4, pB);
    pA = MFMA_BF16(w2r[0][5], av5, pA);  pB = MFMA_BF16(w2r[1][5], av5, pB);
    pA = MFMA_BF16(w2r[0][6], av6, pA);  pB = MFMA_BF16(w2r[1][6], av6, pB);
    pA = MFMA_BF16(w2r[0][7], av7, pA);  pB = MFMA_BF16(w2r[1][7], av7, pB);
#pragma unroll
    for (int n = 0; n < 2; ++n) {
      f32x4 p = n ? pB : pA;
      unsigned wq = 0;
#pragma unroll
      for (int q = 0; q < 4; ++q) {
        float x = p[q] + bv2v[n][q];
        float e2 = __expf(2.f * x);
        float t127 = fmaf(-254.f, __builtin_amdgcn_rcpf(e2 + 1.f), 127.f);  // 127*tanh
        wq |= ((unsigned)((int)rintf(t127) & 255)) << (q * 8);
      }
      ((unsigned*)V2QH)[((2 * wv + n) * 16 + c) * 4 + kg] = wq;
    }
  };
  auto S3 = [&](int T, int lsb_) {  // V2QH x WmL -> part (ls-folded)
    i32x4 aih0 = *(const i32x4*)&V2QH[(0 * 64 + lane) * 16];
    i32x4 aih1 = *(const i32x4*)&V2QH[(1 * 64 + lane) * 16];
    i32x4 aih2 = *(const i32x4*)&V2QH[(2 * 64 + lane) * 16];
    i32x4 aih3 = *(const i32x4*)&V2QH[(3 * 64 + lane) * 16];
    const int nl = (wv < 5) ? 3 : 2;
    const int lb = (wv < 5) ? 3 * wv : 15 + 2 * (wv - 5);
    f32x4 acc = zf;
    for (int li = 0; li < nl; ++li) {
      int l = lb + li;
      const i32x4* bp = (const i32x4*)WmL + l * 256 + lane;
      i32x4 bq0 = bp[0], bq1 = bp[64], bq2 = bp[128], bq3 = bp[192];
      i32x4 PH = MFMA_I8(aih0, bq0, zi);
      PH = MFMA_I8(aih1, bq1, PH);
      PH = MFMA_I8(aih2, bq2, PH);
      PH = MFMA_I8(aih3, bq3, PH);
      f32x4 ls4 = *(const f32x4*)&LSF[T][lsb_][l][kg * 4];
#pragma unroll
      for (int q = 0; q < 4; ++q) acc[q] += ls4[q] * (float)PH[q];
    }
#pragma unroll
    for (int q = 0; q < 4; ++q) part[wv][kg * 4 + q][c] = acc[q];
  };
  auto S4 = [&](int T, int jj, int lsb_, float& y, float& yp, float& bmdc) {
    if (tid < 256) {
      int r = tid >> 4, hh = tid & 15;
      float s = ((part[0][r][hh] + part[1][r][hh]) + (part[2][r][hh] + part[3][r][hh])) +
                ((part[4][r][hh] + part[5][r][hh]) + (part[6][r][hh] + part[7][r][hh]));
      if (jj == 0 || (jj & 1)) {   // interval changed -> recompute bm.ls
        float bmd = 0.f;
#pragma unroll
        for (int l = 0; l < 21; ++l) bmd += LSF[T][lsb_][l][r] * bmL[l * 16 + hh];
        bmdc = bmd;
      }
      float raw = scL[hh] * s + bmdc;
      float yn;
      if (!(jj & 1)) { yp = y + 0.5f * raw; yn = y + raw; }
      else           { y = yp + 0.5f * raw; yn = y; }
      unsigned v = ((unsigned)(jj + 1) << 16) | (unsigned)bf16u(yn);
      __hip_atomic_store(&ybuf[((Gp * 2 + T) * 2 + (jj & 1)) * 2048 + r * 128 + t * 16 + hh],
                         v, __ATOMIC_RELAXED, __HIP_MEMORY_SCOPE_AGENT);
    }
  };
  auto S5 = [&](int T, int jj) {  // poll peers' tags, rebuild YB[T]
    const unsigned tg = (unsigned)(jj + 1);
    const unsigned* pb = ybuf + ((Gp * 2 + T) * 2 + (jj & 1)) * 2048;
    unsigned v0, v1, v2, v3;
#pragma unroll 1
    for (int sp = 0; sp < 60000; ++sp) {
      v0 = __hip_atomic_load(&pb[tid],        __ATOMIC_RELAXED, __HIP_MEMORY_SCOPE_AGENT);
      v1 = __hip_atomic_load(&pb[tid + 512],  __ATOMIC_RELAXED, __HIP_MEMORY_SCOPE_AGENT);
      v2 = __hip_atomic_load(&pb[tid + 1024], __ATOMIC_RELAXED, __HIP_MEMORY_SCOPE_AGENT);
      v3 = __hip_atomic_load(&pb[tid + 1536], __ATOMIC_RELAXED, __HIP_MEMORY_SCOPE_AGENT);
      unsigned mn = min(min(v0 >> 16, v1 >> 16), min(v2 >> 16, v3 >> 16));
      if (mn == tg) break;
    }
    YB[T][tid >> 7][tid & 127] = (u16)(v0 & 0xffffu);
    YB[T][(tid + 512) >> 7][(tid + 512) & 127] = (u16)(v1 & 0xffffu);
    YB[T][(tid + 1024) >> 7][(tid + 1024) & 127] = (u16)(v2 & 0xffffu);
    YB[T][(tid + 1536) >> 7][(tid + 1536) & 127] = (u16)(v3 & 0xffffu);
  };

  __syncthreads();

  // ---- pipeline prologue: tile B runs S1,S2 of sub-step 0
  STAGE(1, 0);
  __syncthreads();
  S1(1);
  __syncthreads();
  S2();
  __syncthreads();

#pragma unroll 1
  for (int j = 0; j < 2 * NSTEPS; ++j) {
    const int step_ = j >> 1, sub_ = j & 1;
    const int lsb_ = (sub_ ? step_ : (step_ > 0 ? step_ - 1 : 0)) & 1;
    // p0: S1(A,j) || S3(B,j)
    if (!sub_) STAGE(0, step_);
    S1(0);
    S3(1, lsb_);
    __syncthreads();
    // p1: store B early, compute S2(A), poll B late
    S4(1, j, lsb_, y1s, yp1s, bmd1);
    S2();
    S5(1, j);
    __syncthreads();
    // p2: S3(A,j) || S1(B,j+1)
    S3(0, lsb_);
    if (j < 2 * NSTEPS - 1) {
      if (sub_) STAGE(1, (j + 1) >> 1);
      S1(1);
    }
    __syncthreads();
    // p3: store A early, compute S2(B,j+1), poll A late
    S4(0, j, lsb_, y0s, yp0s, bmd0);
    if (j < 2 * NSTEPS - 1) S2();
    S5(0, j);
    __syncthreads();
  }

  // ---- logits + softmax (slice-0 WG of each pair; 32 rows)
  if (t == 0) {
    for (int e = tid; e < 32 * 10; e += NTH) {
      int rr = e / 10, cc = e - rr * 10;
      float a = b2[cc];
#pragma unroll 4
      for (int h = 0; h < H; ++h) a += b2f(YB[rr >> 4][rr & 15][h]) * W2[cc * H + h];
      LG[rr][cc] = a;
    }
    __syncthreads();
    if (tid < 32) {
      float mx = -1e30f;
#pragma unroll
      for (int cc = 0; cc < 10; ++cc) mx = fmaxf(mx, LG[tid][cc]);
      float ex[10]; float s = 0.f;
#pragma unroll
      for (int cc = 0; cc < 10; ++cc) { ex[cc] = expf(LG[tid][cc] - mx); s += ex[cc]; }
      float inv = 1.f / s;
#pragma unroll
      for (int cc = 0; cc < 10; ++cc) out[(b0 + tid) * 10 + cc] = ex[cc] * inv;
    }
  }
}

extern "C" void kernel_launch(void* const* d_in, const int* in_sizes, int n_in,
                              void* d_out, int out_size, void* d_ws, size_t ws_size,
                              hipStream_t stream) {
  (void)in_sizes; (void)n_in; (void)out_size; (void)ws_size;
  const float* logsig = (const float*)d_in[1];
  const float* x0     = (const float*)d_in[2];
  const float* Wvf1   = (const float*)d_in[3];
  const float* bvf1   = (const float*)d_in[4];
  const float* Wvf2   = (const float*)d_in[5];
  const float* bvf2   = (const float*)d_in[6];
  const float* Wm     = (const float*)d_in[7];
  const float* bmv    = (const float*)d_in[8];
  const float* W1     = (const float*)d_in[9];
  const float* b1     = (const float*)d_in[10];
  const float* W2     = (const float*)d_in[11];
  const float* b2     = (const float*)d_in[12];
  char* ws = (char*)d_ws;

  prep_scales<<<128, PREPTH, 0, stream>>>(Wm, ws);
  prep_pack<<<3083, PREPTH, 0, stream>>>(Wvf1, Wvf2, Wm, bmv, ws);
  hipMemsetAsync(ws + OFF_YBUF, 0, YBUF_BYTES, stream);  // kill stale tags each call
  rde_main<<<NWG, NTH, 0, stream>>>(logsig, x0, W1, b1, bvf1, bvf2, W2, b2, ws,
                                    (float*)d_out);
}